// Round 17
// baseline (384.457 us; speedup 1.0000x reference)
//
#include <hip/hip_runtime.h>

#define B_ROWS 4096
#define D      512
#define N_EX   20000
#define EXP2   20096     // N_EX padded to multiple of 128
#define MPROJ  24192     // 4096 + 20096 rows projected in one GEMM
#define N_LAB  100
#define LABP2  128       // labels padded to 4x32 (rows 100..127 zero)
#define NT2    157       // EXP2 / 128
#define SPLITS 16

typedef __attribute__((ext_vector_type(8)))  short short8v;   // 8 bf16 (MFMA A/B frag)
typedef __attribute__((ext_vector_type(16))) float f32x16;
typedef __attribute__((ext_vector_type(2)))  int   int2v;
typedef unsigned short u16;

__device__ __forceinline__ u16 f2bf(float x) {
    unsigned u = __builtin_bit_cast(unsigned, x);
    u = u + 0x7FFFu + ((u >> 16) & 1u);          // RNE
    return (u16)(u >> 16);
}
__device__ __forceinline__ float bf2f(u16 h) {
    unsigned u = ((unsigned)h) << 16;
    return __builtin_bit_cast(float, u);
}

__device__ __forceinline__ void gload16(const void* g, void* l) {
    __builtin_amdgcn_global_load_lds((const __attribute__((address_space(1))) void*)g,
                                     (__attribute__((address_space(3))) void*)l, 16, 0, 0);
}

__device__ __forceinline__ unsigned pk_bf16(float a, float b) {
    unsigned r;
    asm("v_cvt_pk_bf16_f32 %0, %1, %2" : "=v"(r) : "v"(a), "v"(b));
    return r;
}

// (a', b') = ( (a.lo32, b.lo32), (a.hi32, b.hi32) )  -- lane-half exchange
__device__ __forceinline__ void swap_halves(unsigned &a, unsigned &b) {
#if __has_builtin(__builtin_amdgcn_permlane32_swap)
    int2v r = __builtin_amdgcn_permlane32_swap((int)a, (int)b, false, false);
    a = (unsigned)r[0]; b = (unsigned)r[1];
#else
    unsigned sa = (unsigned)__shfl_xor((int)a, 32, 64);
    unsigned sb = (unsigned)__shfl_xor((int)b, 32, 64);
    if (threadIdx.x & 32) a = sb; else b = sa;
#endif
}

#define MFMA32(a, b, c) __builtin_amdgcn_mfma_f32_32x32x16_bf16((a), (b), (c), 0, 0, 0)

// ---------------- one-shot bf16 split of all three fp32 inputs ----------------
__global__ __launch_bounds__(256)
void split3_k(const float* __restrict__ f, const float* __restrict__ ex,
              const float* __restrict__ gw, u16* __restrict__ xall,
              u16* __restrict__ wh) {
    int i8 = blockIdx.x * 256 + threadIdx.x;          // one short8 per thread
    int row = i8 >> 6;
    int e = (i8 & 63) * 8;
    const float* src = nullptr;
    u16* dst;
    if (row < B_ROWS) {
        src = &f[(size_t)row * D + e];
        dst = &xall[(size_t)row * D + e];
    } else if (row < B_ROWS + EXP2) {
        int er = row - B_ROWS;
        if (er < N_EX) src = &ex[(size_t)er * D + e];
        dst = &xall[(size_t)row * D + e];
    } else if (row < B_ROWS + EXP2 + D) {
        int wr = row - B_ROWS - EXP2;
        src = &gw[(size_t)wr * D + e];
        dst = &wh[(size_t)wr * D + e];
    } else return;
    short8v h = {0,0,0,0,0,0,0,0};
    if (src) {
        float4 a = *(const float4*)src, b = *(const float4*)(src + 4);
        float v[8] = {a.x,a.y,a.z,a.w,b.x,b.y,b.z,b.w};
        #pragma unroll
        for (int j = 0; j < 8; ++j) h[j] = (short)f2bf(v[j]);
    }
    *(short8v*)dst = h;
}

// ---------------- big 1-pass GEMM: C = A @ B^T, A[M][512] bf16, B[512][512] bf16 ----------------
__global__ __launch_bounds__(512, 4)
void gemm128_k(const u16* __restrict__ A, const u16* __restrict__ B,
               u16* __restrict__ C) {
    __shared__ u16 BUF[2][128][128];     // 64 KiB; row = [A 8 granules | B 8 granules]
    const int tid = threadIdx.x;
    const int l = tid & 63, w = tid >> 6;
    const int wa = w >> 2, wb = w & 3;
    const int l31 = l & 31, l5 = l >> 5;
    const int m0 = blockIdx.x * 128, n0 = blockIdx.y * 128;
    const int qrow_in = l >> 4;
    const int gs = l & 15;

    f32x16 sacc[2] = {};

    auto STAGE = [&](int nx, int kc_) {
        const int kofs = kc_ * 64;
        #pragma unroll
        for (int i = 0; i < 4; ++i) {
            const int q = w * 4 + i;
            const int r = q * 4 + qrow_in;
            const int g = gs ^ (r & 15);
            const u16* src = (g < 8)
                ? &A[(size_t)(m0 + r) * D + kofs + g * 8]
                : &B[(size_t)(n0 + r) * D + kofs + (g - 8) * 8];
            gload16(src, (u16*)&BUF[nx][0][0] + q * 512);
        }
    };

    STAGE(0, 0);
    __syncthreads();
    int cur = 0;
    for (int kc = 0; kc < 8; ++kc) {
        if (kc < 7) STAGE(cur ^ 1, kc + 1);
        const u16* base = &BUF[cur][0][0];
        #pragma unroll
        for (int ks = 0; ks < 4; ++ks) {
            const int gk = ks * 2 + l5;
            short8v aX[2], bW;
            #pragma unroll
            for (int ei = 0; ei < 2; ++ei) {
                int r = wa * 64 + ei * 32 + l31;
                aX[ei] = *(const short8v*)(base + r * 128 + (gk ^ (r & 15)) * 8);
            }
            {
                int r = wb * 32 + l31;
                bW = *(const short8v*)(base + r * 128 + ((gk | 8) ^ (r & 15)) * 8);
            }
            sacc[0] = MFMA32(aX[0], bW, sacc[0]);
            sacc[1] = MFMA32(aX[1], bW, sacc[1]);
        }
        __syncthreads();
        cur ^= 1;
    }
    #pragma unroll
    for (int ei = 0; ei < 2; ++ei)
        #pragma unroll
        for (int r = 0; r < 16; ++r) {
            int row = m0 + wa * 64 + ei * 32 + (r & 3) + 8 * (r >> 2) + 4 * l5;
            int col = n0 + wb * 32 + l31;
            C[(size_t)row * D + col] = f2bf(sacc[ei][r]);
        }
}

// ---------------- inve3[e] = (1/|en_e|)^3 (0 for zero/pad rows), one wave per row ----------------
__global__ __launch_bounds__(256)
void inve3_k(const u16* __restrict__ enh, float* __restrict__ inve3) {
    const int row = blockIdx.x * 4 + (threadIdx.x >> 6);
    const int ln = threadIdx.x & 63;
    if (row >= EXP2) return;
    short8v hv = *(const short8v*)&enh[(size_t)row * D + ln * 8];
    float ss = 0.f;
    #pragma unroll
    for (int j = 0; j < 8; ++j) { float v = bf2f((u16)hv[j]); ss += v * v; }
    #pragma unroll
    for (int off = 32; off > 0; off >>= 1) ss += __shfl_xor(ss, off, 64);
    if (ln == 0) {
        float q = (ss > 0.f) ? rsqrtf(ss) : 0.f;
        inve3[row] = q * q * q;
    }
}

// ---------------- ecr^T blocked: th[lab][e] = bf16((l1norm(exc[e]) @ creps)[lab]) ----------------
__global__ __launch_bounds__(256)
void ecrT_k(const float* __restrict__ exc, const float* __restrict__ creps,
            u16* __restrict__ th) {
    __shared__ float CRT[N_LAB][101];   // CRT[lab][c] = creps[c][lab]
    __shared__ float EX[128][N_LAB];
    __shared__ float INV[128];
    __shared__ u16 OUT[LABP2][128];
    const int tid = threadIdx.x;
    const int e0 = blockIdx.x * 128;
    for (int i = tid; i < N_LAB * N_LAB; i += 256) {
        int c = i / N_LAB, lab = i % N_LAB;
        CRT[lab][c] = creps[i];
    }
    for (int i = tid; i < 128 * N_LAB; i += 256) {
        int el = i / N_LAB, c = i % N_LAB;
        int e = e0 + el;
        EX[el][c] = (e < N_EX) ? exc[(size_t)e * N_LAB + c] : 0.f;
    }
    __syncthreads();
    if (tid < 128) {
        float s = 0.f;
        for (int c = 0; c < N_LAB; ++c) s += fabsf(EX[tid][c]);
        INV[tid] = 1.0f / fmaxf(s, 1e-12f);
    }
    __syncthreads();
    const int lab = tid & 127;
    for (int el = tid >> 7; el < 128; el += 2) {
        float acc = 0.f;
        if (lab < N_LAB) {
            #pragma unroll 4
            for (int c = 0; c < N_LAB; ++c) acc += EX[el][c] * CRT[lab][c];
            acc *= INV[el];
        }
        OUT[lab][el] = f2bf(acc);       // labs 100..127 -> 0
    }
    __syncthreads();
    for (int i = tid; i < LABP2 * 16; i += 256) {
        int lb = i >> 4, ch = i & 15;
        *(short8v*)&th[(size_t)lb * EXP2 + e0 + ch * 8] = *(const short8v*)&OUT[lb][ch * 8];
    }
}

// ---------------- fused main: r11 schedule + inve3 fold + T5 setprio ----------------
// tile 256m x 128e, 512 thr / 8 waves, wave = 64e x 64m.
// S^T = en_raw @ fn_raw^T (1-pass bf16); a3c = S^3 * inve3[e] (invf^3 cancels);
// num += a3c @ WT^T (in-register A-frags via cvt_pk + permlane32_swap).
// Single __syncthreads per phase; 16-slot interleaved swizzle (0 conflicts);
// s_setprio(1) around each MFMA cluster (T5, isolated here for the first time).
__global__ __launch_bounds__(512, 2)
void fused_k(const u16* __restrict__ fnh, const u16* __restrict__ enh,
             const u16* __restrict__ ecth, const float* __restrict__ inve3,
             float* __restrict__ nump, float* __restrict__ denp2) {
    __shared__ u16 SMEM[65536];          // 128 KiB
    u16* ENR = SMEM;                     // [2][8192]  : 128 rows -> 64 lines x 16 slots
    u16* FNR = SMEM + 16384;             // [2][16384] : 256 rows -> 128 lines x 16 slots
    u16* WTB = SMEM + 49152;             // [16384]    : 128 labs x 16 slots

    const int tid = threadIdx.x;
    const int l = tid & 63, w = tid >> 6;
    const int we = w >> 2, wq = w & 3;   // wave: e-half we (64), m-quarter wq (64)
    const int l31 = l & 31, l5 = l >> 5;
    const int wg = blockIdx.x;
    const int split = (wg & 7) + 8 * ((wg >> 3) & 1);
    const int m0 = (wg >> 4) * 256;

    union FragU { short8v s; unsigned u[4]; };

    f32x16 num_acc[2][4] = {};           // [mi][lab-tile]
    float den_th[2] = {0.f, 0.f};

    // interleaved 16-slot staging: dest granule p -> source (row, g)
    auto STAGE_AB = [&](int nx, int t_, int kc_) {
        const int e0_ = t_ * 128, kofs = kc_ * 64;
        #pragma unroll
        for (int i = 0; i < 2; ++i) {    // en: 2 instr/thread
            const int p = w * 128 + i * 64 + l;
            const int line = p >> 4, q = (p & 15) ^ (line & 15);
            const int row = line * 2 + (q >> 3), g = q & 7;
            gload16(&enh[(size_t)(e0_ + row) * D + kofs + g * 8],
                    ENR + nx * 8192 + p * 8);
        }
        #pragma unroll
        for (int i = 0; i < 4; ++i) {    // fn: 4 instr/thread
            const int p = w * 256 + i * 64 + l;
            const int line = p >> 4, q = (p & 15) ^ (line & 15);
            const int row = line * 2 + (q >> 3), g = q & 7;
            gload16(&fnh[(size_t)(m0 + row) * D + kofs + g * 8],
                    FNR + nx * 16384 + p * 8);
        }
    };
    auto STAGE_WT = [&](int t_) {
        const int e0_ = t_ * 128;
        #pragma unroll
        for (int i = 0; i < 4; ++i) {    // 4 instr/thread
            const int p = w * 256 + i * 64 + l;
            const int lab = p >> 4, g = p & 15;
            gload16(&ecth[(size_t)lab * EXP2 + e0_ + ((g ^ (lab & 15)) * 8)],
                    WTB + p * 8);
        }
    };
    auto ldfrag = [&](const u16* base, int r, int gk) -> short8v {
        int line = r >> 1;
        int slot = (((r & 1) << 3) | gk) ^ (line & 15);
        return *(const short8v*)(base + line * 128 + slot * 8);
    };

    STAGE_AB(0, split, 0);
    __syncthreads();
    int cur = 0;

    for (int t = split; t < NT2; t += SPLITS) {
        const int e0 = t * 128;
        f32x16 sacc[2][2] = {};          // [ei][mi]
        for (int kc = 0; kc < 8; ++kc) {
            if (kc < 7) STAGE_AB(cur ^ 1, t, kc + 1);
            else        STAGE_WT(t);
            const u16* eb = ENR + cur * 8192;
            const u16* fb = FNR + cur * 16384;
            __builtin_amdgcn_s_setprio(1);
            #pragma unroll
            for (int ks = 0; ks < 4; ++ks) {
                const int gk = ks * 2 + l5;
                short8v aE[2], bF[2];
                #pragma unroll
                for (int ei = 0; ei < 2; ++ei)
                    aE[ei] = ldfrag(eb, we * 64 + ei * 32 + l31, gk);
                #pragma unroll
                for (int mi = 0; mi < 2; ++mi)
                    bF[mi] = ldfrag(fb, wq * 64 + mi * 32 + l31, gk);
                #pragma unroll
                for (int ei = 0; ei < 2; ++ei)
                    #pragma unroll
                    for (int mi = 0; mi < 2; ++mi)
                        sacc[ei][mi] = MFMA32(aE[ei], bF[mi], sacc[ei][mi]);
            }
            __builtin_amdgcn_s_setprio(0);
            __syncthreads();
            if (kc < 7) cur ^= 1;
        }
        // ---- num phase: WTB ready; stage next t's kc=0 into buf[cur^1]
        const int tn = t + SPLITS;
        if (tn < NT2) STAGE_AB(cur ^ 1, tn, 0);
        #pragma unroll
        for (int ei = 0; ei < 2; ++ei) {
            float iv[16];
            #pragma unroll
            for (int r = 0; r < 16; ++r)
                iv[r] = inve3[e0 + we * 64 + ei * 32 + (r & 3) + 8 * (r >> 2) + 4 * l5];
            FragU fr[2][2];              // [mi][c]
            #pragma unroll
            for (int mi = 0; mi < 2; ++mi) {
                float a3[16];
                #pragma unroll
                for (int r = 0; r < 16; ++r) {
                    float sv = sacc[ei][mi][r];
                    float c3 = sv * sv * sv * iv[r];
                    a3[r] = c3;
                    den_th[mi] += fabsf(c3);
                }
                #pragma unroll
                for (int c = 0; c < 2; ++c) {
                    unsigned p01 = pk_bf16(a3[c*8+0], a3[c*8+1]);
                    unsigned p23 = pk_bf16(a3[c*8+2], a3[c*8+3]);
                    unsigned p45 = pk_bf16(a3[c*8+4], a3[c*8+5]);
                    unsigned p67 = pk_bf16(a3[c*8+6], a3[c*8+7]);
                    swap_halves(p01, p45);
                    swap_halves(p23, p67);
                    fr[mi][c].u[0] = p01; fr[mi][c].u[1] = p23;
                    fr[mi][c].u[2] = p45; fr[mi][c].u[3] = p67;
                }
            }
            __builtin_amdgcn_s_setprio(1);
            #pragma unroll
            for (int c = 0; c < 2; ++c) {
                const int gw2 = (we * 4 + ei * 2 + c) * 2 + l5;   // e-granule 0..15
                #pragma unroll
                for (int lt = 0; lt < 4; ++lt) {
                    int row = lt * 32 + l31;
                    short8v wf = *(const short8v*)(WTB + row * 128 + (gw2 ^ (row & 15)) * 8);
                    num_acc[0][lt] = MFMA32(fr[0][c].s, wf, num_acc[0][lt]);
                    num_acc[1][lt] = MFMA32(fr[1][c].s, wf, num_acc[1][lt]);
                }
            }
            __builtin_amdgcn_s_setprio(0);
        }
        __syncthreads();
        cur ^= 1;
    }

    // den: lanes l / l+32 hold same m, disjoint e
    #pragma unroll
    for (int mi = 0; mi < 2; ++mi) {
        float v = den_th[mi];
        v += __shfl_xor(v, 32, 64);
        if (l5 == 0)
            denp2[((size_t)split * 2 + we) * B_ROWS + m0 + wq * 64 + mi * 32 + l31] = v;
    }

    // num: merge e-half partials through SMEM (f32 [128][128] = 64KB), two wq-halves
    float* SMf = (float*)SMEM;
    __syncthreads();
    #pragma unroll
    for (int half = 0; half < 2; ++half) {
        if (we == 1 && (wq >> 1) == half) {
            #pragma unroll
            for (int mi = 0; mi < 2; ++mi)
                #pragma unroll
                for (int lt = 0; lt < 4; ++lt)
                    #pragma unroll
                    for (int r = 0; r < 16; ++r) {
                        int rowf = (r & 3) + 8 * (r >> 2) + 4 * l5;
                        int lrow = (wq & 1) * 64 + mi * 32 + rowf;
                        SMf[lrow * 128 + lt * 32 + l31] = num_acc[mi][lt][r];
                    }
        }
        __syncthreads();
        if (we == 0 && (wq >> 1) == half) {
            #pragma unroll
            for (int mi = 0; mi < 2; ++mi)
                #pragma unroll
                for (int lt = 0; lt < 4; ++lt)
                    #pragma unroll
                    for (int r = 0; r < 16; ++r) {
                        int rowf = (r & 3) + 8 * (r >> 2) + 4 * l5;
                        int lrow = (wq & 1) * 64 + mi * 32 + rowf;
                        float v = num_acc[mi][lt][r] + SMf[lrow * 128 + lt * 32 + l31];
                        int m = m0 + wq * 64 + mi * 32 + rowf;
                        nump[((size_t)split * B_ROWS + m) * LABP2 + lt * 32 + l31] = v;
                    }
        }
        __syncthreads();
    }
}

// ---------------- finalize ----------------
__global__ __launch_bounds__(128)
void finalize_k(const float* __restrict__ nump, const float* __restrict__ denp2,
                float* __restrict__ out) {
    const int row = blockIdx.x, tid = threadIdx.x;
    float den = 0.f;
    for (int s = 0; s < 2 * SPLITS; ++s)
        den += denp2[(size_t)s * B_ROWS + row];
    if (tid < N_LAB) {
        float acc = 0.f;
        for (int s = 0; s < SPLITS; ++s)
            acc += nump[((size_t)s * B_ROWS + row) * LABP2 + tid];
        out[(size_t)row * N_LAB + tid] = acc / fmaxf(den, 1e-12f);
    }
}

extern "C" void kernel_launch(void* const* d_in, const int* in_sizes, int n_in,
                              void* d_out, int out_size, void* d_ws, size_t ws_size,
                              hipStream_t stream) {
    (void)in_sizes; (void)n_in; (void)out_size; (void)ws_size;
    const float* features    = (const float*)d_in[0];
    const float* g_weight    = (const float*)d_in[1];
    const float* ex_features = (const float*)d_in[2];
    const float* ex_classes  = (const float*)d_in[3];
    const float* class_reps  = (const float*)d_in[4];
    float* out = (float*)d_out;

    size_t off = 0;
    auto alloc = [&](size_t bytes) {
        void* p = (char*)d_ws + off;
        off += (bytes + 255) & ~(size_t)255;
        return p;
    };
    u16* fnh = (u16*)alloc((size_t)B_ROWS * D * 2);                     // 4.2 MB
    u16* enh = (u16*)alloc((size_t)EXP2 * D * 2);                       // 20.6 MB (contiguous after fnh)
    u16* ecth = (u16*)alloc((size_t)LABP2 * EXP2 * 2);                  // 5.1 MB
    u16* wh  = (u16*)alloc((size_t)D * D * 2);                          // 0.5 MB
    float* inve3 = (float*)alloc((size_t)EXP2 * 4);                     // 0.08 MB
    float* nump  = (float*)alloc((size_t)SPLITS * B_ROWS * LABP2 * 4);  // 33.6 MB
    float* denp2 = (float*)alloc((size_t)2 * SPLITS * B_ROWS * 4);      // 0.5 MB
    u16* xall = (u16*)nump;   // alias: 24.8 MB input staging, dead before nump written

    const int tot_rows = B_ROWS + EXP2 + D;
    split3_k<<<(tot_rows * 64 + 255) / 256, 256, 0, stream>>>(
        features, ex_features, g_weight, xall, wh);
    gemm128_k<<<dim3(MPROJ / 128, 4), 512, 0, stream>>>(xall, wh, fnh);
    inve3_k<<<(EXP2 + 3) / 4, 256, 0, stream>>>(enh, inve3);
    ecrT_k<<<NT2, 256, 0, stream>>>(ex_classes, class_reps, ecth);
    fused_k<<<256, 512, 0, stream>>>(fnh, enh, ecth, inve3, nump, denp2);
    finalize_k<<<B_ROWS, 128, 0, stream>>>(nump, denp2, out);
}

// Round 18
// 375.979 us; speedup vs baseline: 1.0225x; 1.0225x over previous
//
#include <hip/hip_runtime.h>

#define B_ROWS 4096
#define D      512
#define N_EX   20000
#define EXP2   20096     // N_EX padded to multiple of 128
#define MPROJ  24192     // 4096 + 20096 rows projected in one GEMM
#define N_LAB  100
#define LABP2  128       // labels padded to 4x32 (rows 100..127 zero)
#define NT2    157       // EXP2 / 128
#define SPLITS 16

typedef __attribute__((ext_vector_type(8)))  short short8v;   // 8 bf16 (MFMA A/B frag)
typedef __attribute__((ext_vector_type(16))) float f32x16;
typedef __attribute__((ext_vector_type(2)))  int   int2v;
typedef unsigned short u16;

__device__ __forceinline__ u16 f2bf(float x) {
    unsigned u = __builtin_bit_cast(unsigned, x);
    u = u + 0x7FFFu + ((u >> 16) & 1u);          // RNE
    return (u16)(u >> 16);
}
__device__ __forceinline__ float bf2f(u16 h) {
    unsigned u = ((unsigned)h) << 16;
    return __builtin_bit_cast(float, u);
}

__device__ __forceinline__ void gload16(const void* g, void* l) {
    __builtin_amdgcn_global_load_lds((const __attribute__((address_space(1))) void*)g,
                                     (__attribute__((address_space(3))) void*)l, 16, 0, 0);
}

__device__ __forceinline__ unsigned pk_bf16(float a, float b) {
    unsigned r;
    asm("v_cvt_pk_bf16_f32 %0, %1, %2" : "=v"(r) : "v"(a), "v"(b));
    return r;
}

// (a', b') = ( (a.lo32, b.lo32), (a.hi32, b.hi32) )  -- lane-half exchange
__device__ __forceinline__ void swap_halves(unsigned &a, unsigned &b) {
#if __has_builtin(__builtin_amdgcn_permlane32_swap)
    int2v r = __builtin_amdgcn_permlane32_swap((int)a, (int)b, false, false);
    a = (unsigned)r[0]; b = (unsigned)r[1];
#else
    unsigned sa = (unsigned)__shfl_xor((int)a, 32, 64);
    unsigned sb = (unsigned)__shfl_xor((int)b, 32, 64);
    if (threadIdx.x & 32) a = sb; else b = sa;
#endif
}

#define MFMA32(a, b, c) __builtin_amdgcn_mfma_f32_32x32x16_bf16((a), (b), (c), 0, 0, 0)

// ---------------- one-shot bf16 split of all three fp32 inputs ----------------
__global__ __launch_bounds__(256)
void split3_k(const float* __restrict__ f, const float* __restrict__ ex,
              const float* __restrict__ gw, u16* __restrict__ xall,
              u16* __restrict__ wh) {
    int i8 = blockIdx.x * 256 + threadIdx.x;          // one short8 per thread
    int row = i8 >> 6;
    int e = (i8 & 63) * 8;
    const float* src = nullptr;
    u16* dst;
    if (row < B_ROWS) {
        src = &f[(size_t)row * D + e];
        dst = &xall[(size_t)row * D + e];
    } else if (row < B_ROWS + EXP2) {
        int er = row - B_ROWS;
        if (er < N_EX) src = &ex[(size_t)er * D + e];
        dst = &xall[(size_t)row * D + e];
    } else if (row < B_ROWS + EXP2 + D) {
        int wr = row - B_ROWS - EXP2;
        src = &gw[(size_t)wr * D + e];
        dst = &wh[(size_t)wr * D + e];
    } else return;
    short8v h = {0,0,0,0,0,0,0,0};
    if (src) {
        float4 a = *(const float4*)src, b = *(const float4*)(src + 4);
        float v[8] = {a.x,a.y,a.z,a.w,b.x,b.y,b.z,b.w};
        #pragma unroll
        for (int j = 0; j < 8; ++j) h[j] = (short)f2bf(v[j]);
    }
    *(short8v*)dst = h;
}

// ---------------- big 1-pass GEMM: C = A @ B^T, A[M][512] bf16, B[512][512] bf16 ----------------
__global__ __launch_bounds__(512, 4)
void gemm128_k(const u16* __restrict__ A, const u16* __restrict__ B,
               u16* __restrict__ C) {
    __shared__ u16 BUF[2][128][128];     // 64 KiB; row = [A 8 granules | B 8 granules]
    const int tid = threadIdx.x;
    const int l = tid & 63, w = tid >> 6;
    const int wa = w >> 2, wb = w & 3;
    const int l31 = l & 31, l5 = l >> 5;
    const int m0 = blockIdx.x * 128, n0 = blockIdx.y * 128;
    const int qrow_in = l >> 4;
    const int gs = l & 15;

    f32x16 sacc[2] = {};

    auto STAGE = [&](int nx, int kc_) {
        const int kofs = kc_ * 64;
        #pragma unroll
        for (int i = 0; i < 4; ++i) {
            const int q = w * 4 + i;
            const int r = q * 4 + qrow_in;
            const int g = gs ^ (r & 15);
            const u16* src = (g < 8)
                ? &A[(size_t)(m0 + r) * D + kofs + g * 8]
                : &B[(size_t)(n0 + r) * D + kofs + (g - 8) * 8];
            gload16(src, (u16*)&BUF[nx][0][0] + q * 512);
        }
    };

    STAGE(0, 0);
    __syncthreads();
    int cur = 0;
    for (int kc = 0; kc < 8; ++kc) {
        if (kc < 7) STAGE(cur ^ 1, kc + 1);
        const u16* base = &BUF[cur][0][0];
        #pragma unroll
        for (int ks = 0; ks < 4; ++ks) {
            const int gk = ks * 2 + l5;
            short8v aX[2], bW;
            #pragma unroll
            for (int ei = 0; ei < 2; ++ei) {
                int r = wa * 64 + ei * 32 + l31;
                aX[ei] = *(const short8v*)(base + r * 128 + (gk ^ (r & 15)) * 8);
            }
            {
                int r = wb * 32 + l31;
                bW = *(const short8v*)(base + r * 128 + ((gk | 8) ^ (r & 15)) * 8);
            }
            sacc[0] = MFMA32(aX[0], bW, sacc[0]);
            sacc[1] = MFMA32(aX[1], bW, sacc[1]);
        }
        __syncthreads();
        cur ^= 1;
    }
    #pragma unroll
    for (int ei = 0; ei < 2; ++ei)
        #pragma unroll
        for (int r = 0; r < 16; ++r) {
            int row = m0 + wa * 64 + ei * 32 + (r & 3) + 8 * (r >> 2) + 4 * l5;
            int col = n0 + wb * 32 + l31;
            C[(size_t)row * D + col] = f2bf(sacc[ei][r]);
        }
}

// ---------------- in-place L2 row-normalize, one wave per row ----------------
__global__ __launch_bounds__(256)
void l2norm_k(u16* __restrict__ hi, int nrows) {
    const int row = blockIdx.x * 4 + (threadIdx.x >> 6);
    const int ln = threadIdx.x & 63;
    if (row >= nrows) return;
    const size_t base = (size_t)row * D + ln * 8;
    short8v hv = *(short8v*)&hi[base];
    float v[8]; float ss = 0.f;
    #pragma unroll
    for (int j = 0; j < 8; ++j) { v[j] = bf2f((u16)hv[j]); ss += v[j] * v[j]; }
    #pragma unroll
    for (int off = 32; off > 0; off >>= 1) ss += __shfl_xor(ss, off, 64);
    float inv = 1.0f / fmaxf(sqrtf(ss), 1e-12f);
    short8v ho;
    #pragma unroll
    for (int j = 0; j < 8; ++j) ho[j] = (short)f2bf(v[j] * inv);
    *(short8v*)&hi[base] = ho;
}

// ---------------- ecr^T blocked: th[lab][e] = bf16((l1norm(exc[e]) @ creps)[lab]) ----------------
__global__ __launch_bounds__(256)
void ecrT_k(const float* __restrict__ exc, const float* __restrict__ creps,
            u16* __restrict__ th) {
    __shared__ float CRT[N_LAB][101];   // CRT[lab][c] = creps[c][lab]
    __shared__ float EX[128][N_LAB];
    __shared__ float INV[128];
    __shared__ u16 OUT[LABP2][128];
    const int tid = threadIdx.x;
    const int e0 = blockIdx.x * 128;
    for (int i = tid; i < N_LAB * N_LAB; i += 256) {
        int c = i / N_LAB, lab = i % N_LAB;
        CRT[lab][c] = creps[i];
    }
    for (int i = tid; i < 128 * N_LAB; i += 256) {
        int el = i / N_LAB, c = i % N_LAB;
        int e = e0 + el;
        EX[el][c] = (e < N_EX) ? exc[(size_t)e * N_LAB + c] : 0.f;
    }
    __syncthreads();
    if (tid < 128) {
        float s = 0.f;
        for (int c = 0; c < N_LAB; ++c) s += fabsf(EX[tid][c]);
        INV[tid] = 1.0f / fmaxf(s, 1e-12f);
    }
    __syncthreads();
    const int lab = tid & 127;
    for (int el = tid >> 7; el < 128; el += 2) {
        float acc = 0.f;
        if (lab < N_LAB) {
            #pragma unroll 4
            for (int c = 0; c < N_LAB; ++c) acc += EX[el][c] * CRT[lab][c];
            acc *= INV[el];
        }
        OUT[lab][el] = f2bf(acc);       // labs 100..127 -> 0
    }
    __syncthreads();
    for (int i = tid; i < LABP2 * 16; i += 256) {
        int lb = i >> 4, ch = i & 15;
        *(short8v*)&th[(size_t)lb * EXP2 + e0 + ch * 8] = *(const short8v*)&OUT[lb][ch * 8];
    }
}

// ---------------- fused main: tile 256m x 128e, wave = 64e x 64m ----------------
// s^T = en @ fn^T (32x32x16, 1-pass), cube in-register,
// num += a3 @ WT^T (A-frags via cvt_pk + permlane32_swap).
// Single __syncthreads per phase; 16-slot interleaved swizzle (0 conflicts).
// XCD clustering: 1D grid of 256; split=(wg&7)+8*((wg>>3)&1).
__global__ __launch_bounds__(512, 2)
void fused_k(const u16* __restrict__ fnh, const u16* __restrict__ enh,
             const u16* __restrict__ ecth,
             float* __restrict__ nump, float* __restrict__ denp2) {
    __shared__ u16 SMEM[65536];          // 128 KiB
    u16* ENR = SMEM;                     // [2][8192]  : 128 rows -> 64 lines x 16 slots
    u16* FNR = SMEM + 16384;             // [2][16384] : 256 rows -> 128 lines x 16 slots
    u16* WTB = SMEM + 49152;             // [16384]    : 128 labs x 16 slots

    const int tid = threadIdx.x;
    const int l = tid & 63, w = tid >> 6;
    const int we = w >> 2, wq = w & 3;   // wave: e-half we (64), m-quarter wq (64)
    const int l31 = l & 31, l5 = l >> 5;
    const int wg = blockIdx.x;
    const int split = (wg & 7) + 8 * ((wg >> 3) & 1);
    const int m0 = (wg >> 4) * 256;

    union FragU { short8v s; unsigned u[4]; };

    f32x16 num_acc[2][4] = {};           // [mi][lab-tile]
    float den_th[2] = {0.f, 0.f};

    // interleaved 16-slot staging: dest granule p -> source (row, g)
    auto STAGE_AB = [&](int nx, int t_, int kc_) {
        const int e0_ = t_ * 128, kofs = kc_ * 64;
        #pragma unroll
        for (int i = 0; i < 2; ++i) {    // en: 1024 granules, 2 instr/wave
            const int p = w * 128 + i * 64 + l;
            const int line = p >> 4, q = (p & 15) ^ (line & 15);
            const int row = line * 2 + (q >> 3), g = q & 7;
            gload16(&enh[(size_t)(e0_ + row) * D + kofs + g * 8],
                    ENR + nx * 8192 + p * 8);
        }
        #pragma unroll
        for (int i = 0; i < 4; ++i) {    // fn: 2048 granules, 4 instr/wave
            const int p = w * 256 + i * 64 + l;
            const int line = p >> 4, q = (p & 15) ^ (line & 15);
            const int row = line * 2 + (q >> 3), g = q & 7;
            gload16(&fnh[(size_t)(m0 + row) * D + kofs + g * 8],
                    FNR + nx * 16384 + p * 8);
        }
    };
    auto STAGE_WT = [&](int t_) {
        const int e0_ = t_ * 128;
        #pragma unroll
        for (int i = 0; i < 4; ++i) {    // 2048 granules, 4 instr/wave
            const int p = w * 256 + i * 64 + l;
            const int lab = p >> 4, g = p & 15;
            gload16(&ecth[(size_t)lab * EXP2 + e0_ + ((g ^ (lab & 15)) * 8)],
                    WTB + p * 8);
        }
    };
    auto ldfrag = [&](const u16* base, int r, int gk) -> short8v {
        int line = r >> 1;
        int slot = (((r & 1) << 3) | gk) ^ (line & 15);
        return *(const short8v*)(base + line * 128 + slot * 8);
    };

    STAGE_AB(0, split, 0);
    __syncthreads();
    int cur = 0;

    for (int t = split; t < NT2; t += SPLITS) {
        f32x16 sacc[2][2] = {};          // [ei][mi]
        for (int kc = 0; kc < 8; ++kc) {
            if (kc < 7) STAGE_AB(cur ^ 1, t, kc + 1);
            else        STAGE_WT(t);
            const u16* eb = ENR + cur * 8192;
            const u16* fb = FNR + cur * 16384;
            #pragma unroll
            for (int ks = 0; ks < 4; ++ks) {
                const int gk = ks * 2 + l5;
                short8v aE[2], bF[2];
                #pragma unroll
                for (int ei = 0; ei < 2; ++ei)
                    aE[ei] = ldfrag(eb, we * 64 + ei * 32 + l31, gk);
                #pragma unroll
                for (int mi = 0; mi < 2; ++mi)
                    bF[mi] = ldfrag(fb, wq * 64 + mi * 32 + l31, gk);
                #pragma unroll
                for (int ei = 0; ei < 2; ++ei)
                    #pragma unroll
                    for (int mi = 0; mi < 2; ++mi)
                        sacc[ei][mi] = MFMA32(aE[ei], bF[mi], sacc[ei][mi]);
            }
            __syncthreads();
            if (kc < 7) cur ^= 1;
        }
        // ---- num phase: WTB ready; stage next t's kc=0 into buf[cur^1]
        const int tn = t + SPLITS;
        if (tn < NT2) STAGE_AB(cur ^ 1, tn, 0);
        #pragma unroll
        for (int ei = 0; ei < 2; ++ei) {
            FragU fr[2][2];              // [mi][c]
            #pragma unroll
            for (int mi = 0; mi < 2; ++mi) {
                float a3[16];
                #pragma unroll
                for (int r = 0; r < 16; ++r) {
                    float sv = sacc[ei][mi][r];
                    float c3 = sv * sv * sv;
                    a3[r] = c3;
                    den_th[mi] += fabsf(c3);
                }
                #pragma unroll
                for (int c = 0; c < 2; ++c) {
                    unsigned p01 = pk_bf16(a3[c*8+0], a3[c*8+1]);
                    unsigned p23 = pk_bf16(a3[c*8+2], a3[c*8+3]);
                    unsigned p45 = pk_bf16(a3[c*8+4], a3[c*8+5]);
                    unsigned p67 = pk_bf16(a3[c*8+6], a3[c*8+7]);
                    swap_halves(p01, p45);
                    swap_halves(p23, p67);
                    fr[mi][c].u[0] = p01; fr[mi][c].u[1] = p23;
                    fr[mi][c].u[2] = p45; fr[mi][c].u[3] = p67;
                }
            }
            #pragma unroll
            for (int c = 0; c < 2; ++c) {
                const int gw2 = (we * 4 + ei * 2 + c) * 2 + l5;   // e-granule 0..15
                #pragma unroll
                for (int lt = 0; lt < 4; ++lt) {
                    int row = lt * 32 + l31;
                    short8v wf = *(const short8v*)(WTB + row * 128 + (gw2 ^ (row & 15)) * 8);
                    num_acc[0][lt] = MFMA32(fr[0][c].s, wf, num_acc[0][lt]);
                    num_acc[1][lt] = MFMA32(fr[1][c].s, wf, num_acc[1][lt]);
                }
            }
        }
        __syncthreads();
        cur ^= 1;
    }

    // den: lanes l / l+32 hold same m, disjoint e
    #pragma unroll
    for (int mi = 0; mi < 2; ++mi) {
        float v = den_th[mi];
        v += __shfl_xor(v, 32, 64);
        if (l5 == 0)
            denp2[((size_t)split * 2 + we) * B_ROWS + m0 + wq * 64 + mi * 32 + l31] = v;
    }

    // num: merge e-half partials through SMEM (f32 [128][128] = 64KB), two wq-halves
    float* SMf = (float*)SMEM;
    __syncthreads();
    #pragma unroll
    for (int half = 0; half < 2; ++half) {
        if (we == 1 && (wq >> 1) == half) {
            #pragma unroll
            for (int mi = 0; mi < 2; ++mi)
                #pragma unroll
                for (int lt = 0; lt < 4; ++lt)
                    #pragma unroll
                    for (int r = 0; r < 16; ++r) {
                        int rowf = (r & 3) + 8 * (r >> 2) + 4 * l5;
                        int lrow = (wq & 1) * 64 + mi * 32 + rowf;
                        SMf[lrow * 128 + lt * 32 + l31] = num_acc[mi][lt][r];
                    }
        }
        __syncthreads();
        if (we == 0 && (wq >> 1) == half) {
            #pragma unroll
            for (int mi = 0; mi < 2; ++mi)
                #pragma unroll
                for (int lt = 0; lt < 4; ++lt)
                    #pragma unroll
                    for (int r = 0; r < 16; ++r) {
                        int rowf = (r & 3) + 8 * (r >> 2) + 4 * l5;
                        int lrow = (wq & 1) * 64 + mi * 32 + rowf;
                        float v = num_acc[mi][lt][r] + SMf[lrow * 128 + lt * 32 + l31];
                        int m = m0 + wq * 64 + mi * 32 + rowf;
                        nump[((size_t)split * B_ROWS + m) * LABP2 + lt * 32 + l31] = v;
                    }
        }
        __syncthreads();
    }
}

// ---------------- finalize ----------------
__global__ __launch_bounds__(128)
void finalize_k(const float* __restrict__ nump, const float* __restrict__ denp2,
                float* __restrict__ out) {
    const int row = blockIdx.x, tid = threadIdx.x;
    float den = 0.f;
    for (int s = 0; s < 2 * SPLITS; ++s)
        den += denp2[(size_t)s * B_ROWS + row];
    if (tid < N_LAB) {
        float acc = 0.f;
        for (int s = 0; s < SPLITS; ++s)
            acc += nump[((size_t)s * B_ROWS + row) * LABP2 + tid];
        out[(size_t)row * N_LAB + tid] = acc / fmaxf(den, 1e-12f);
    }
}

extern "C" void kernel_launch(void* const* d_in, const int* in_sizes, int n_in,
                              void* d_out, int out_size, void* d_ws, size_t ws_size,
                              hipStream_t stream) {
    (void)in_sizes; (void)n_in; (void)out_size; (void)ws_size;
    const float* features    = (const float*)d_in[0];
    const float* g_weight    = (const float*)d_in[1];
    const float* ex_features = (const float*)d_in[2];
    const float* ex_classes  = (const float*)d_in[3];
    const float* class_reps  = (const float*)d_in[4];
    float* out = (float*)d_out;

    size_t off = 0;
    auto alloc = [&](size_t bytes) {
        void* p = (char*)d_ws + off;
        off += (bytes + 255) & ~(size_t)255;
        return p;
    };
    u16* fnh = (u16*)alloc((size_t)B_ROWS * D * 2);                     // 4.2 MB
    u16* enh = (u16*)alloc((size_t)EXP2 * D * 2);                       // 20.6 MB (contiguous after fnh)
    u16* ecth = (u16*)alloc((size_t)LABP2 * EXP2 * 2);                  // 5.1 MB
    u16* wh  = (u16*)alloc((size_t)D * D * 2);                          // 0.5 MB
    float* nump  = (float*)alloc((size_t)SPLITS * B_ROWS * LABP2 * 4);  // 33.6 MB
    float* denp2 = (float*)alloc((size_t)2 * SPLITS * B_ROWS * 4);      // 0.5 MB
    u16* xall = (u16*)nump;   // alias: 24.8 MB input staging, dead before nump written

    const int tot_rows = B_ROWS + EXP2 + D;
    split3_k<<<(tot_rows * 64 + 255) / 256, 256, 0, stream>>>(
        features, ex_features, g_weight, xall, wh);
    gemm128_k<<<dim3(MPROJ / 128, 4), 512, 0, stream>>>(xall, wh, fnh);
    l2norm_k<<<(MPROJ + 3) / 4, 256, 0, stream>>>(fnh, MPROJ);
    ecrT_k<<<NT2, 256, 0, stream>>>(ex_classes, class_reps, ecth);
    fused_k<<<256, 512, 0, stream>>>(fnh, enh, ecth, nump, denp2);
    finalize_k<<<B_ROWS, 128, 0, stream>>>(nump, denp2, out);
}